// Round 1
// baseline (1646.001 us; speedup 1.0000x reference)
//
#include <hip/hip_runtime.h>

#define BATCH 16384
#define NCAT 26
#define VOCAB 100000
#define EDIM 128

typedef __attribute__((ext_vector_type(8))) short bf16x8;
typedef __attribute__((ext_vector_type(4))) float f32x4;

// ---- bf16 helpers (raw-bits, RNE) ----
__device__ __forceinline__ unsigned short f2b(float f) {
    unsigned int u = __float_as_uint(f);
    u += 0x7fffu + ((u >> 16) & 1u);
    return (unsigned short)(u >> 16);
}
__device__ __forceinline__ float b2f(unsigned short h) {
    return __uint_as_float(((unsigned int)h) << 16);
}
__device__ __forceinline__ bf16x8 zero8() {
    union { bf16x8 v; unsigned short s[8]; } t;
#pragma unroll
    for (int i = 0; i < 8; i++) t.s[i] = 0;
    return t.v;
}
__device__ __forceinline__ bf16x8 load_cvt8(const float* p) {
    const float4* q = (const float4*)p;
    float4 u = q[0], v = q[1];
    union { bf16x8 v8; unsigned short s[8]; } t;
    t.s[0] = f2b(u.x); t.s[1] = f2b(u.y); t.s[2] = f2b(u.z); t.s[3] = f2b(u.w);
    t.s[4] = f2b(v.x); t.s[5] = f2b(v.y); t.s[6] = f2b(v.z); t.s[7] = f2b(v.w);
    return t.v8;
}
__device__ __forceinline__ void async16(const void* g, void* l) {
    __builtin_amdgcn_global_load_lds(
        (const __attribute__((address_space(1))) void*)g,
        (__attribute__((address_space(3))) void*)l, 16, 0, 0);
}

// ---- ws layout (element offsets into (unsigned short*)ws) ----
#define E_WD1   0u            // 512 x 32
#define E_WD2   16384u        // 256 x 512
#define E_WDF   147456u       // 128 x 256
#define E_WT1   180224u       // 1024 x 512
#define E_WT2   704512u       // 1024 x 1024
#define E_WT3   1753088u      // 512 x 1024
#define E_WT4   2277376u      // 256 x 512
#define E_DXB   2408448u      // B x 32
#define E_H1    2932736u      // B x 512
#define E_H2    11321344u     // B x 256
#define E_DENSE 15515648u     // B x 128
#define E_X1    17612800u     // B x 512
#define E_T1    26001408u     // B x 1024
#define E_T2    42778624u     // B x 1024
#define E_T3    59555840u     // B x 512
#define E_X4    67944448u     // B x 256
#define WC_TOT  2408448

// ---- weight transpose+convert: out[n][k] = bf16(W[k][n]), zero-padded K ----
__global__ void wconv_kernel(const float* __restrict__ w0, const float* __restrict__ w1,
                             const float* __restrict__ w2, const float* __restrict__ w3,
                             const float* __restrict__ w4, const float* __restrict__ w5,
                             const float* __restrict__ w6, unsigned short* __restrict__ u16) {
    int gid = blockIdx.x * 256 + threadIdx.x;
    if (gid >= WC_TOT) return;
    const float* in; int N, K, ks; unsigned int obase; int local;
    if      (gid < 16384)  { in = w0; N = 512;  K = 13;   ks = 5;  obase = E_WD1; local = gid; }
    else if (gid < 147456) { in = w1; N = 256;  K = 512;  ks = 9;  obase = E_WD2; local = gid - 16384; }
    else if (gid < 180224) { in = w2; N = 128;  K = 256;  ks = 8;  obase = E_WDF; local = gid - 147456; }
    else if (gid < 704512) { in = w3; N = 1024; K = 479;  ks = 9;  obase = E_WT1; local = gid - 180224; }
    else if (gid < 1753088){ in = w4; N = 1024; K = 1024; ks = 10; obase = E_WT2; local = gid - 704512; }
    else if (gid < 2277376){ in = w5; N = 512;  K = 1024; ks = 10; obase = E_WT3; local = gid - 1753088; }
    else                   { in = w6; N = 256;  K = 512;  ks = 9;  obase = E_WT4; local = gid - 2277376; }
    int n = local >> ks;
    int k = local & ((1 << ks) - 1);
    float v = (k < K) ? in[(size_t)k * N + n] : 0.f;
    u16[obase + (unsigned int)local] = f2b(v);
}

// ---- dense_x (B x 13 fp32) -> (B x 32 bf16, zero-padded) ----
__global__ void dxconv_kernel(const float* __restrict__ dx, unsigned short* __restrict__ out) {
    int gid = blockIdx.x * 256 + threadIdx.x;
    if (gid >= BATCH * 32) return;
    int b = gid >> 5, k = gid & 31;
    out[gid] = (k < 13) ? f2b(dx[b * 13 + k]) : 0;
}

// ---- m97-style GEMM: C[M,N] = relu(A[M,K] @ BT[N,K]^T + bias), bf16 in/out ----
__global__ __launch_bounds__(256, 2) void gemm_bt(
    const unsigned short* __restrict__ A, const unsigned short* __restrict__ BT,
    const float* __restrict__ bias, unsigned short* __restrict__ C,
    int M, int N, int K, int relu) {
    __shared__ __align__(16) unsigned short As[128 * 32];
    __shared__ __align__(16) unsigned short Bs[128 * 32];
    int tid = threadIdx.x;
    int tileM = blockIdx.y * 128, tileN = blockIdx.x * 128;
    int w = tid >> 6, lane = tid & 63;
    int wm = w & 1, wn = w >> 1;
    int lr = lane & 15, lq = lane >> 4;

    f32x4 acc[4][4];
#pragma unroll
    for (int i = 0; i < 4; i++)
#pragma unroll
        for (int j = 0; j < 4; j++) acc[i][j] = 0.f;

    int rowA = tid >> 2;            // 0..63
    int colE = (tid & 3) * 8;       // element col within 32
    const unsigned short* gA = A + (size_t)(tileM + rowA) * K + colE;
    const unsigned short* gB = BT + (size_t)(tileN + rowA) * K + colE;
    unsigned short* lA = As + tid * 8;
    unsigned short* lB = Bs + tid * 8;

    for (int k0 = 0; k0 < K; k0 += 32) {
        async16(gA + k0, lA);
        async16(gA + (size_t)64 * K + k0, lA + 64 * 32);
        async16(gB + k0, lB);
        async16(gB + (size_t)64 * K + k0, lB + 64 * 32);
        __syncthreads();
        bf16x8 af[4], bfr[4];
#pragma unroll
        for (int i = 0; i < 4; i++)
            af[i] = *(const bf16x8*)&As[(wm * 64 + i * 16 + lr) * 32 + lq * 8];
#pragma unroll
        for (int i = 0; i < 4; i++)
            bfr[i] = *(const bf16x8*)&Bs[(wn * 64 + i * 16 + lr) * 32 + lq * 8];
#pragma unroll
        for (int mi = 0; mi < 4; mi++)
#pragma unroll
            for (int ni = 0; ni < 4; ni++)
                acc[mi][ni] = __builtin_amdgcn_mfma_f32_16x16x32_bf16(af[mi], bfr[ni], acc[mi][ni], 0, 0, 0);
        __syncthreads();
    }
#pragma unroll
    for (int mi = 0; mi < 4; mi++)
#pragma unroll
        for (int ni = 0; ni < 4; ni++) {
            int col = tileN + wn * 64 + ni * 16 + lr;
            float bv = bias[col];
#pragma unroll
            for (int r = 0; r < 4; r++) {
                int row = tileM + wm * 64 + mi * 16 + lq * 4 + r;
                float v = acc[mi][ni][r] + bv;
                if (relu) v = fmaxf(v, 0.f);
                C[(size_t)row * N + col] = f2b(v);
            }
        }
}

// ---- interaction: per-wave sample, S = Z Z^T upper-tri -> X1[b][0..351),
//      dense -> X1[b][351..479), zero pad [479..512) ----
#define TRIOFF(i) ((i) * 26 - (i) * ((i) - 1) / 2)
__global__ __launch_bounds__(256) void interact_kernel(
    const float* __restrict__ emb, const int* __restrict__ idx,
    const unsigned short* __restrict__ dense, unsigned short* __restrict__ X1) {
    int tid = threadIdx.x;
    int w = tid >> 6, lane = tid & 63;
    int b = blockIdx.x * 4 + w;
    int lr = lane & 15, lq = lane >> 4;

    const float* src0 = emb + ((size_t)lr * VOCAB + (size_t)idx[b * NCAT + lr]) * EDIM;
    int r1 = 16 + lr;
    const float* src1 = (r1 < NCAT)
        ? emb + ((size_t)r1 * VOCAB + (size_t)idx[b * NCAT + r1]) * EDIM : (const float*)0;

    f32x4 c00 = 0.f, c01 = 0.f, c11 = 0.f;
#pragma unroll
    for (int kstep = 0; kstep < 4; kstep++) {
        int col = kstep * 32 + lq * 8;
        bf16x8 f0 = load_cvt8(src0 + col);
        bf16x8 f1;
        if (r1 < NCAT)       f1 = load_cvt8(src1 + col);
        else if (r1 == NCAT) f1 = *(const bf16x8*)&dense[(size_t)b * EDIM + col];
        else                 f1 = zero8();
        c00 = __builtin_amdgcn_mfma_f32_16x16x32_bf16(f0, f0, c00, 0, 0, 0);
        c01 = __builtin_amdgcn_mfma_f32_16x16x32_bf16(f0, f1, c01, 0, 0, 0);
        c11 = __builtin_amdgcn_mfma_f32_16x16x32_bf16(f1, f1, c11, 0, 0, 0);
    }
    unsigned short* xr = X1 + (size_t)b * 512;
#pragma unroll
    for (int r = 0; r < 4; r++) {  // tile (0,0): i = lq*4+r, j = lr
        int i = lq * 4 + r, j = lr;
        if (i < j) xr[TRIOFF(i) + (j - i - 1)] = f2b(c00[r]);
    }
#pragma unroll
    for (int r = 0; r < 4; r++) {  // tile (0,1): i = lq*4+r, j = 16+lr
        int i = lq * 4 + r, j = 16 + lr;
        if (j < 27) xr[TRIOFF(i) + (j - i - 1)] = f2b(c01[r]);
    }
#pragma unroll
    for (int r = 0; r < 4; r++) {  // tile (1,1): i = 16+lq*4+r, j = 16+lr
        int i = 16 + lq * 4 + r, j = 16 + lr;
        if (i < j && j < 27) xr[TRIOFF(i) + (j - i - 1)] = f2b(c11[r]);
    }
    for (int t = lane; t < 161; t += 64)
        xr[351 + t] = (t < 128) ? dense[(size_t)b * EDIM + t] : (unsigned short)0;
}

// ---- final: out[b] = sigmoid(x4[b,0:256] . Wo + bo), one wave per row ----
__global__ __launch_bounds__(256) void final_kernel(
    const unsigned short* __restrict__ x4, const float* __restrict__ Wo,
    const float* __restrict__ bo, float* __restrict__ out) {
    int w = threadIdx.x >> 6, lane = threadIdx.x & 63;
    int b = blockIdx.x * 4 + w;
    const unsigned short* xr = x4 + (size_t)b * 256;
    ushort4 xv = *(const ushort4*)(xr + lane * 4);
    float4  wv = *(const float4*)(Wo + lane * 4);
    float s = b2f(xv.x) * wv.x + b2f(xv.y) * wv.y + b2f(xv.z) * wv.z + b2f(xv.w) * wv.w;
#pragma unroll
    for (int off = 32; off; off >>= 1) s += __shfl_down(s, off);
    if (lane == 0) out[b] = 1.f / (1.f + expf(-(s + bo[0])));
}

extern "C" void kernel_launch(void* const* d_in, const int* in_sizes, int n_in,
                              void* d_out, int out_size, void* d_ws, size_t ws_size,
                              hipStream_t stream) {
    const float* dense_x = (const float*)d_in[0];
    const int*   cat_idx = (const int*)d_in[1];
    const float* emb     = (const float*)d_in[2];
    const float* Wd1 = (const float*)d_in[3];  const float* bd1 = (const float*)d_in[4];
    const float* Wd2 = (const float*)d_in[5];  const float* bd2 = (const float*)d_in[6];
    const float* Wdf = (const float*)d_in[7];  const float* bdf = (const float*)d_in[8];
    const float* Wt1 = (const float*)d_in[9];  const float* bt1 = (const float*)d_in[10];
    const float* Wt2 = (const float*)d_in[11]; const float* bt2 = (const float*)d_in[12];
    const float* Wt3 = (const float*)d_in[13]; const float* bt3 = (const float*)d_in[14];
    const float* Wt4 = (const float*)d_in[15]; const float* bt4 = (const float*)d_in[16];
    const float* Wo  = (const float*)d_in[17]; const float* bo  = (const float*)d_in[18];
    float* out = (float*)d_out;
    unsigned short* u16 = (unsigned short*)d_ws;

    wconv_kernel<<<(WC_TOT + 255) / 256, 256, 0, stream>>>(Wd1, Wd2, Wdf, Wt1, Wt2, Wt3, Wt4, u16);
    dxconv_kernel<<<(BATCH * 32) / 256, 256, 0, stream>>>(dense_x, u16 + E_DXB);

    gemm_bt<<<dim3(4, 128), 256, 0, stream>>>(u16 + E_DXB, u16 + E_WD1, bd1, u16 + E_H1, BATCH, 512, 32, 1);
    gemm_bt<<<dim3(2, 128), 256, 0, stream>>>(u16 + E_H1, u16 + E_WD2, bd2, u16 + E_H2, BATCH, 256, 512, 1);
    gemm_bt<<<dim3(1, 128), 256, 0, stream>>>(u16 + E_H2, u16 + E_WDF, bdf, u16 + E_DENSE, BATCH, 128, 256, 1);

    interact_kernel<<<BATCH / 4, 256, 0, stream>>>(emb, cat_idx, u16 + E_DENSE, u16 + E_X1);

    gemm_bt<<<dim3(8, 128), 256, 0, stream>>>(u16 + E_X1, u16 + E_WT1, bt1, u16 + E_T1, BATCH, 1024, 512, 1);
    gemm_bt<<<dim3(8, 128), 256, 0, stream>>>(u16 + E_T1, u16 + E_WT2, bt2, u16 + E_T2, BATCH, 1024, 1024, 1);
    gemm_bt<<<dim3(4, 128), 256, 0, stream>>>(u16 + E_T2, u16 + E_WT3, bt3, u16 + E_T3, BATCH, 512, 1024, 1);
    gemm_bt<<<dim3(2, 128), 256, 0, stream>>>(u16 + E_T3, u16 + E_WT4, bt4, u16 + E_X4, BATCH, 256, 512, 1);

    final_kernel<<<BATCH / 4, 256, 0, stream>>>(u16 + E_X4, Wo, bo, out);
}